// Round 3
// baseline (660.945 us; speedup 1.0000x reference)
//
#include <hip/hip_runtime.h>

// 8-bit ripple-carry adder on {0,1} floats, bitwise formulation.
// R2 post-mortem: one-item-per-thread capped at 3.1 TB/s HBM (4.5 TB/s
// logical) -- wave churn / shallow MLP, not access density. R3: persistent
// grid-stride kernel, 2048 blocks x 256 = 32 waves/CU exactly; each thread
// processes 32 half-rows in unroll-4 batches (all loads of a batch issued
// before compute -> ~144 B/lane in flight).
//
// Bitwise trick: inputs are exactly 0.0f/1.0f (0x00000000/0x3F800000), so
// s = a^b^c, cout = (a&b)|(c&(a^b)) on raw uint32 reproduces the reference
// bit-for-bit.
//
// Thread item idx (half-row): row r = idx>>1; odd idx = columns 4..7 (LSB
// side), even idx = columns 0..3 (MSB side, writes final carry). Ripple is
// .w,.z,.y,.x within each half; LSB lane's carry reaches its even partner
// via __shfl_xor(...,1) (idx parity == lane parity since stride is even).

#define UNROLL 4

__device__ __forceinline__ unsigned fa(unsigned a, unsigned b, unsigned c,
                                       unsigned& s) {
    unsigned x = a ^ b;
    s = x ^ c;
    return (a & b) | (c & x);
}

__device__ __forceinline__ void half_chain(const uint4& a, const uint4& b,
                                           unsigned cin, uint4& s,
                                           unsigned& cout) {
    unsigned c = cin;
    c = fa(a.w, b.w, c, s.w);
    c = fa(a.z, b.z, c, s.z);
    c = fa(a.y, b.y, c, s.y);
    c = fa(a.x, b.x, c, s.x);
    cout = c;
}

__global__ __launch_bounds__(256) void Adder8Bit_kernel(
    const uint4* __restrict__ A4,      // [2N] dense uint4 view of A[N,8]
    const uint4* __restrict__ B4,      // [2N]
    const unsigned* __restrict__ Cin,  // [N]
    uint4*       __restrict__ S4,      // [2N] sums output
    unsigned*    __restrict__ Cout,    // [N]  carry output
    int halves)                        // = 2N
{
    const int tid    = blockIdx.x * blockDim.x + threadIdx.x;
    const int stride = gridDim.x * blockDim.x;          // even
    const int isLSB  = tid & 1;                         // == lane parity

    for (int base = tid; base < halves; base += stride * UNROLL) {
        uint4 a[UNROLL], b[UNROLL];
        unsigned ci[UNROLL];
        int idx[UNROLL];
        bool ok[UNROLL];

        // Issue the whole batch of loads before any compute.
        #pragma unroll
        for (int k = 0; k < UNROLL; ++k) {
            idx[k] = base + k * stride;
            ok[k]  = idx[k] < halves;
            if (ok[k]) {
                a[k]  = A4[idx[k]];
                b[k]  = B4[idx[k]];
                ci[k] = Cin[idx[k] >> 1];
            }
        }

        #pragma unroll
        for (int k = 0; k < UNROLL; ++k) {
            // Phase 1: chain with cin = Cin[row]; only LSB lanes' carry-out
            // is meaningful, shipped to the even partner lane.
            uint4 s1;
            unsigned c1;
            half_chain(a[k], b[k], ci[k], s1, c1);
            unsigned cprev = (unsigned)__shfl_xor((int)c1, 1);

            // Phase 2: correct carry-in (LSB lanes keep Cin[row]).
            unsigned cin = isLSB ? ci[k] : cprev;
            uint4 s2;
            unsigned c2;
            half_chain(a[k], b[k], cin, s2, c2);

            if (ok[k]) {
                S4[idx[k]] = s2;
                if (!isLSB) Cout[idx[k] >> 1] = c2;  // MSB half: final carry
            }
        }
    }
}

extern "C" void kernel_launch(void* const* d_in, const int* in_sizes, int n_in,
                              void* d_out, int out_size, void* d_ws, size_t ws_size,
                              hipStream_t stream) {
    const unsigned* A   = (const unsigned*)d_in[0];  // [N,8]
    const unsigned* B   = (const unsigned*)d_in[1];  // [N,8]
    const unsigned* Cin = (const unsigned*)d_in[2];  // [N,1]
    unsigned* out = (unsigned*)d_out;                // [8N] sums ++ [N] carry

    const int N      = in_sizes[0] / 8;
    const int halves = 2 * N;

    uint4*    S4   = (uint4*)out;
    unsigned* Cout = out + (size_t)8 * N;

    // 2048 blocks x 256 threads = 2^21 threads = 32 waves/CU on 256 CUs.
    const int block = 256;
    int grid = 2048;
    // Safety for small N: don't launch more threads than items.
    int maxGrid = (halves + block - 1) / block;
    if (grid > maxGrid) grid = maxGrid;

    Adder8Bit_kernel<<<grid, block, 0, stream>>>(
        (const uint4*)A, (const uint4*)B, Cin, S4, Cout, halves);
}

// Round 4
// 639.074 us; speedup vs baseline: 1.0342x; 1.0342x over previous
//
#include <hip/hip_runtime.h>

// 8-bit ripple-carry adder on {0,1} floats, bitwise formulation.
//
// R3 post-mortem: persistent + grid-strided BATCH items (32 MB apart)
// regressed to 2.5 TB/s -- page/TLB spread, occupancy 61%. R4 keeps the
// persistent structure but batches BLOCK-contiguously: the 4 unrolled items
// are k*blockDim (=256 items = 4 KB) apart, so each block walks a dense
// 16 KB window per sweep step; outer sweep stride covers the array.
//
// Bitwise trick: inputs are exactly 0.0f/1.0f (0x00000000/0x3F800000), so
// s = a^b^c, cout = (a&b)|(c&(a^b)) on raw uint32 reproduces the reference
// bit-for-bit.
//
// Half-row per thread: item idx -> row idx>>1; odd idx = cols 4..7 (LSB
// half), even idx = cols 0..3 (MSB half, writes final carry). Ripple is
// .w,.z,.y,.x in each half; LSB carry crosses to the even partner lane via
// __shfl_xor(...,1) (idx parity == lane parity: all strides are even).

#define UNROLL 4

__device__ __forceinline__ unsigned fa(unsigned a, unsigned b, unsigned c,
                                       unsigned& s) {
    unsigned x = a ^ b;
    s = x ^ c;
    return (a & b) | (c & x);
}

__device__ __forceinline__ void half_chain(const uint4& a, const uint4& b,
                                           unsigned cin, uint4& s,
                                           unsigned& cout) {
    unsigned c = cin;
    c = fa(a.w, b.w, c, s.w);
    c = fa(a.z, b.z, c, s.z);
    c = fa(a.y, b.y, c, s.y);
    c = fa(a.x, b.x, c, s.x);
    cout = c;
}

__device__ __forceinline__ void do_item(
    int idx, int isLSB,
    const uint4 a, const uint4 b, const unsigned ci,
    uint4* __restrict__ S4, unsigned* __restrict__ Cout)
{
    // Phase 1: chain with cin = Cin[row]; only LSB lanes' carry matters.
    uint4 s1; unsigned c1;
    half_chain(a, b, ci, s1, c1);
    unsigned cprev = (unsigned)__shfl_xor((int)c1, 1);

    // Phase 2: correct carry-in (LSB lanes keep Cin[row]).
    uint4 s2; unsigned c2;
    half_chain(a, b, isLSB ? ci : cprev, s2, c2);

    S4[idx] = s2;
    if (!isLSB) Cout[idx >> 1] = c2;  // MSB half writes the final carry
}

__global__ __launch_bounds__(256) void Adder8Bit_kernel(
    const uint4* __restrict__ A4,      // [2N] dense uint4 view of A[N,8]
    const uint4* __restrict__ B4,      // [2N]
    const unsigned* __restrict__ Cin,  // [N]
    uint4*       __restrict__ S4,      // [2N] sums output
    unsigned*    __restrict__ Cout,    // [N]  carry output
    int halves,                        // = 2N
    int full)                          // largest multiple of sweep span
{
    const int tid    = threadIdx.x;
    const int bdim   = blockDim.x;                   // 256
    const int span   = bdim * UNROLL;                // items per block/sweep
    const int sweep  = gridDim.x * span;             // items per sweep, all blocks
    const int isLSB  = tid & 1;                      // == idx parity (below)

    // Main loop: no per-item bounds checks (halves % sweep handled by tail).
    for (int base = blockIdx.x * span + tid; base < full; base += sweep) {
        uint4 a[UNROLL], b[UNROLL];
        unsigned ci[UNROLL];

        #pragma unroll
        for (int k = 0; k < UNROLL; ++k) {
            int idx = base + k * bdim;
            a[k]  = A4[idx];
            b[k]  = B4[idx];
            ci[k] = Cin[idx >> 1];
        }

        #pragma unroll
        for (int k = 0; k < UNROLL; ++k) {
            do_item(base + k * bdim, isLSB, a[k], b[k], ci[k], S4, Cout);
        }
    }

    // Tail (empty when halves % sweep == 0, which holds for N = 2^23).
    for (int idx = full + blockIdx.x * bdim + tid; idx < halves;
         idx += gridDim.x * bdim) {
        uint4 a = A4[idx];
        uint4 b = B4[idx];
        unsigned ci = Cin[idx >> 1];
        do_item(idx, isLSB, a, b, ci, S4, Cout);
    }
}

extern "C" void kernel_launch(void* const* d_in, const int* in_sizes, int n_in,
                              void* d_out, int out_size, void* d_ws, size_t ws_size,
                              hipStream_t stream) {
    const unsigned* A   = (const unsigned*)d_in[0];  // [N,8]
    const unsigned* B   = (const unsigned*)d_in[1];  // [N,8]
    const unsigned* Cin = (const unsigned*)d_in[2];  // [N,1]
    unsigned* out = (unsigned*)d_out;                // [8N] sums ++ [N] carry

    const int N      = in_sizes[0] / 8;
    const int halves = 2 * N;

    uint4*    S4   = (uint4*)out;
    unsigned* Cout = out + (size_t)8 * N;

    // 2048 blocks x 256 threads = 8 WG/CU = 32 waves/CU on 256 CUs.
    const int block = 256;
    int grid = 2048;
    int maxGrid = (halves + block - 1) / block;
    if (grid > maxGrid) grid = maxGrid;

    const int sweep = grid * block * UNROLL;
    const int full  = (halves / sweep) * sweep;

    Adder8Bit_kernel<<<grid, block, 0, stream>>>(
        (const uint4*)A, (const uint4*)B, Cin, S4, Cout, halves, full);
}

// Round 6
// 605.159 us; speedup vs baseline: 1.0922x; 1.0560x over previous
//
#include <hip/hip_runtime.h>

// 8-bit ripple-carry adder on {0,1} floats, bitwise formulation.
//
// R1/R2/R4 post-mortem: three structurally different versions (1 item/thread,
// grid-spread persistent, block-dense persistent) ALL plateau at ~190-200 us
// (~4.4 TB/s logical, ~3.0 TB/s HBM) -- MLP/occupancy/access-density are
// exonerated. R5/R6 theory: cache-allocating loads+stores on purely streaming
// data fight their own evictions in L2/L3; fillBuffer (streaming policy) hits
// 6.3 TB/s in the same capture. Fix: nontemporal (nt) hints on all streams.
// R5 failed compile: __builtin_nontemporal_* rejects HIP_vector_type; use a
// native clang ext_vector_type(4) instead.
//
// Bitwise trick: inputs are exactly 0.0f/1.0f (0x00000000/0x3F800000), so
// s = a^b^c, cout = (a&b)|(c&(a^b)) on raw uint32 reproduces the reference
// bit-for-bit.
//
// Half-row per thread (R2 structure): thread t -> row r=t>>1; odd t = cols
// 4..7 (LSB half), even t = cols 0..3 (MSB half, writes final carry).
// Ripple is elem 3,2,1,0 within each half; the LSB half's carry crosses to
// its even partner lane via __shfl_xor(...,1).

typedef unsigned uvec4 __attribute__((ext_vector_type(4)));

__device__ __forceinline__ unsigned fa(unsigned a, unsigned b, unsigned c,
                                       unsigned& s) {
    unsigned x = a ^ b;
    s = x ^ c;
    return (a & b) | (c & x);
}

__device__ __forceinline__ void half_chain(const uvec4& a, const uvec4& b,
                                           unsigned cin, uvec4& s,
                                           unsigned& cout) {
    unsigned c = cin, t;
    c = fa(a.w, b.w, c, t); s.w = t;
    c = fa(a.z, b.z, c, t); s.z = t;
    c = fa(a.y, b.y, c, t); s.y = t;
    c = fa(a.x, b.x, c, t); s.x = t;
    cout = c;
}

__global__ __launch_bounds__(256) void Adder8Bit_kernel(
    const uvec4* __restrict__ A4,      // [2N] dense uvec4 view of A[N,8]
    const uvec4* __restrict__ B4,      // [2N]
    const unsigned* __restrict__ Cin,  // [N]
    uvec4*       __restrict__ S4,      // [2N] sums output
    unsigned*    __restrict__ Cout,    // [N]  carry output
    int halves)                        // = 2N
{
    int t = blockIdx.x * blockDim.x + threadIdx.x;
    if (t >= halves) return;

    int r     = t >> 1;
    int isLSB = t & 1;  // lane parity == t parity (block multiple of 64)

    uvec4 a = __builtin_nontemporal_load(A4 + t);
    uvec4 b = __builtin_nontemporal_load(B4 + t);
    unsigned cin0 = __builtin_nontemporal_load(Cin + r);

    // Phase 1: chain with cin = Cin[r]; only the LSB half's carry matters.
    uvec4 s1;
    unsigned c1;
    half_chain(a, b, cin0, s1, c1);

    // Even (MSB) lane fetches its odd partner's carry-out.
    unsigned cprev = (unsigned)__shfl_xor((int)c1, 1);

    // Phase 2: redo with the correct carry-in (LSB lanes keep Cin[r]).
    uvec4 s2;
    unsigned c2;
    half_chain(a, b, isLSB ? cin0 : cprev, s2, c2);

    __builtin_nontemporal_store(s2, S4 + t);
    if (!isLSB) __builtin_nontemporal_store(c2, Cout + r);
}

extern "C" void kernel_launch(void* const* d_in, const int* in_sizes, int n_in,
                              void* d_out, int out_size, void* d_ws, size_t ws_size,
                              hipStream_t stream) {
    const unsigned* A   = (const unsigned*)d_in[0];  // [N,8]
    const unsigned* B   = (const unsigned*)d_in[1];  // [N,8]
    const unsigned* Cin = (const unsigned*)d_in[2];  // [N,1]
    unsigned* out = (unsigned*)d_out;                // [8N] sums ++ [N] carry

    const int N      = in_sizes[0] / 8;
    const int halves = 2 * N;

    uvec4*    S4   = (uvec4*)out;
    unsigned* Cout = out + (size_t)8 * N;

    const int block = 256;
    const int grid  = (halves + block - 1) / block;

    Adder8Bit_kernel<<<grid, block, 0, stream>>>(
        (const uvec4*)A, (const uvec4*)B, Cin, S4, Cout, halves);
}